// Round 4
// baseline (1746.733 us; speedup 1.0000x reference)
//
#include <hip/hip_runtime.h>
#include <hip/hip_bf16.h>
#include <stdint.h>

// LevelReasoning on MI355X — round 4: 256-tile 8-wave counted-vmcnt split GEMM.
// io-format activations: row = 512 ch = 4-slot*32B chunks {8 bf16 hi | 8 bf16 lo},
// K-tile t = bytes [t*128, t*128+128) of each 2048B row.
// sgemm256: BM=256, BK=32, 8 waves (2x4), 2-deep LDS dbuf, counted vmcnt(8),
// raw s_barrier phases with setprio around MFMA clusters, XOR bank swizzle
// applied on BOTH global-source and LDS-read sides, XCD-chunked block swizzle.

using bf16 = __hip_bfloat16;
typedef __attribute__((ext_vector_type(8))) short short8;
typedef __attribute__((ext_vector_type(4))) float f32x4;

__device__ inline uint16_t f2b_bits(float f) {
  bf16 h = __float2bfloat16(f);
  return __builtin_bit_cast(uint16_t, h);
}
__device__ inline float b2f_bits(uint16_t u) { return __uint_as_float(((uint32_t)u) << 16); }
__device__ inline float bflo(uint32_t u) { return __uint_as_float((u & 0xffffu) << 16); }
__device__ inline float bfhi(uint32_t u) { return __uint_as_float(u & 0xffff0000u); }
__device__ inline void split2(float v, uint16_t& hi, uint16_t& lo) {
  hi = f2b_bits(v);
  lo = f2b_bits(v - b2f_bits(hi));
}
__device__ inline float h16(const uint4& u, int e) {
  uint32_t wrd = ((const uint32_t*)&u)[e >> 1];
  return (e & 1) ? bfhi(wrd) : bflo(wrd);
}

typedef const __attribute__((address_space(1))) void* gas_ptr;
typedef __attribute__((address_space(3))) void* las_ptr;
__device__ inline void gload16(const void* g, void* l) {
  __builtin_amdgcn_global_load_lds((gas_ptr)g, (las_ptr)l, 16, 0, 0);
}

// ---------------- f32 -> bf16 (plain, for Wb) ----------------
__global__ __launch_bounds__(256) void cvt4(const float* __restrict__ in,
                                            bf16* __restrict__ out, int n4) {
  int i = blockIdx.x * 256 + threadIdx.x;
  const int stride = gridDim.x * 256;
  for (; i < n4; i += stride) {
    float4 v = ((const float4*)in)[i];
    uint32_t lo = (uint32_t)f2b_bits(v.x) | ((uint32_t)f2b_bits(v.y) << 16);
    uint32_t hi = (uint32_t)f2b_bits(v.z) | ((uint32_t)f2b_bits(v.w) << 16);
    ((uint2*)out)[i] = make_uint2(lo, hi);
  }
}

// ---------------- fold weight to io-format: W' = g*W*diag(s), b' = g*(b + t@W.T) ----------------
__global__ __launch_bounds__(512) void fold_w_io(const float* __restrict__ Wsrc,
                                                 const float* __restrict__ bsrc,
                                                 const float* __restrict__ sv,
                                                 const float* __restrict__ tv,
                                                 const float* __restrict__ gamp,
                                                 char* __restrict__ Wio,
                                                 float* __restrict__ bout) {
  const int row = blockIdx.x, c = threadIdx.x;
  __shared__ float red[512];
  const float wv = Wsrc[(size_t)row * 512 + c];
  const float g = gamp ? gamp[0] : 1.0f;
  const float s = sv ? sv[c] : 1.0f;
  uint16_t hb, lb;
  split2(g * wv * s, hb, lb);
  char* p = Wio + (size_t)row * 2048 + (c >> 3) * 32 + (c & 7) * 2;
  *(uint16_t*)p = hb;
  *(uint16_t*)(p + 16) = lb;
  red[c] = tv ? wv * tv[c] : 0.0f;
  __syncthreads();
#pragma unroll
  for (int off = 256; off > 0; off >>= 1) {
    if (c < off) red[c] += red[c + off];
    __syncthreads();
  }
  if (c == 0) bout[row] = g * (bsrc[row] + red[0]);
}

// ---------------- 256-tile split GEMM, 8 waves, counted vmcnt ----------------
// AMODE 0: A = io-format split bf16 (2KB rows). AMODE 1: A = f32 (2KB rows), split in-reg.
// EPI 0: outf[row*N+col]=acc+bias. EPI 1: io-format out. EPI 2: plain bf16, pitch 512.
// LDS tile layout (per plane-agnostic): pos(r,sp,q) = r*128 + sp*32 + q*16 holding
// global (r, s=sp^(r&3), p=q^((r>>2)&1)) — 2-way banks on frag reads, linear DMA dest.
template <int AMODE, int EPI, int BN>
__global__ __launch_bounds__(512, 1) void sgemm256(const char* __restrict__ A,
                                                   const char* __restrict__ Wio,
                                                   const float* __restrict__ bias,
                                                   float* __restrict__ outf,
                                                   char* __restrict__ outb, int N) {
  constexpr int NFR = BN / 64;      // B frags per wave (n dir)
  constexpr int BCH = BN / 64;      // B 1KB-chunks per wave per tile
  constexpr int PER_BUF = 32768 + BN * 128;
  __shared__ __align__(16) char lds[2 * PER_BUF];
  const int tid = threadIdx.x, w = tid >> 6, l = tid & 63;

  // XCD-chunked bijective block swizzle (nwg % 8 == 0 for all our grids)
  const int nwgx = gridDim.x;
  const int raw = blockIdx.y * nwgx + blockIdx.x;
  const int cpx = (nwgx * gridDim.y) >> 3;
  const int work = (raw & 7) * cpx + (raw >> 3);
  const int bm = (work / nwgx) * 256;
  const int bn = (work % nwgx) * BN;

  // staging lane geometry: lane l covers row (base + l>>3), swizzled 32B slot+16B piece
  const int ssl = ((((l >> 1) & 3) ^ ((l >> 3) & 3)) << 5) | (((l & 1) ^ ((l >> 5) & 1)) << 4);
  const char* Asrc = A + (size_t)(bm + w * 32 + (l >> 3)) * 2048 + ssl;
  const char* Bsrc = Wio + (size_t)(bn + w * (BCH * 8) + (l >> 3)) * 2048 + ssl;

  // fragment-read geometry
  const int lrow = l & 15, lk = l >> 4;
  const int wr = w >> 2, wc = w & 3;  // 2x4 wave grid; wave tile 128 x (BN/4)
  const int sw32 = (lk ^ (lrow & 3)) * 32;
  const int hi16 = ((lrow >> 2) & 1) * 16;
  const int afr = (wr * 128 + lrow) * 128 + sw32;               // + mi*2048 (+hi16/lo)
  const int bfr = 32768 + (wc * (BN / 4) + lrow) * 128 + sw32;  // + ni*2048

  f32x4 acc[8][NFR] = {};

  auto stage = [&](int buf, int t) {
    char* ab = lds + buf * PER_BUF + w * 4096;
    const char* as = Asrc + (size_t)t * 128;
#pragma unroll
    for (int k = 0; k < 4; ++k) gload16(as + (size_t)k * 16384, ab + k * 1024);
    char* bbf = lds + buf * PER_BUF + 32768 + w * (BCH * 1024);
    const char* bs = Bsrc + (size_t)t * 128;
#pragma unroll
    for (int k = 0; k < BCH; ++k) gload16(bs + (size_t)k * 16384, bbf + k * 1024);
  };

  stage(0, 0);
  int cur = 0;
  for (int t = 0; t < 16; ++t) {
    if (t < 15) {
      stage(cur ^ 1, t + 1);  // keep next tile in flight across all barriers
      if constexpr (BN == 256) {
        asm volatile("s_waitcnt vmcnt(8)" ::: "memory");
      } else {
        asm volatile("s_waitcnt vmcnt(6)" ::: "memory");
      }
    } else {
      asm volatile("s_waitcnt vmcnt(0)" ::: "memory");
    }
    __builtin_amdgcn_s_barrier();  // tile t visible to all waves
    asm volatile("" ::: "memory");

    const char* bp = lds + cur * PER_BUF;
    short8 bh[NFR], bl[NFR];
#pragma unroll
    for (int ni = 0; ni < NFR; ++ni) {
      bh[ni] = *(const short8*)(bp + bfr + ni * 2048 + hi16);
      bl[ni] = *(const short8*)(bp + bfr + ni * 2048 + (hi16 ^ 16));
    }
#pragma unroll
    for (int q = 0; q < 4; ++q) {
      short8 ah[2], al[2];
#pragma unroll
      for (int u = 0; u < 2; ++u) {
        const int mi = q * 2 + u;
        if constexpr (AMODE == 0) {
          ah[u] = *(const short8*)(bp + afr + mi * 2048 + hi16);
          al[u] = *(const short8*)(bp + afr + mi * 2048 + (hi16 ^ 16));
        } else {
          float4 f0 = *(const float4*)(bp + afr + mi * 2048 + hi16);
          float4 f1 = *(const float4*)(bp + afr + mi * 2048 + (hi16 ^ 16));
          const float fv[8] = {f0.x, f0.y, f0.z, f0.w, f1.x, f1.y, f1.z, f1.w};
#pragma unroll
          for (int e = 0; e < 8; ++e) {
            uint16_t hb, lb;
            split2(fv[e], hb, lb);
            ah[u][e] = (short)hb;
            al[u][e] = (short)lb;
          }
        }
      }
      __builtin_amdgcn_s_barrier();
      asm volatile("" ::: "memory");
      __builtin_amdgcn_s_setprio(1);
#pragma unroll
      for (int u = 0; u < 2; ++u)
#pragma unroll
        for (int ni = 0; ni < NFR; ++ni) {
          f32x4& a = acc[q * 2 + u][ni];
          a = __builtin_amdgcn_mfma_f32_16x16x32_bf16(ah[u], bh[ni], a, 0, 0, 0);
          a = __builtin_amdgcn_mfma_f32_16x16x32_bf16(ah[u], bl[ni], a, 0, 0, 0);
          a = __builtin_amdgcn_mfma_f32_16x16x32_bf16(al[u], bh[ni], a, 0, 0, 0);
        }
      __builtin_amdgcn_s_setprio(0);
      __builtin_amdgcn_s_barrier();
      asm volatile("" ::: "memory");
    }
    cur ^= 1;
  }

#pragma unroll
  for (int mi = 0; mi < 8; ++mi) {
    const int row = bm + wr * 128 + mi * 16 + lk * 4;
#pragma unroll
    for (int ni = 0; ni < NFR; ++ni) {
      const int col = bn + wc * (BN / 4) + ni * 16 + lrow;
      const float bc = bias[col];
#pragma unroll
      for (int j = 0; j < 4; ++j) {
        const float vv = acc[mi][ni][j] + bc;
        if constexpr (EPI == 0) {
          outf[(size_t)(row + j) * N + col] = vv;
        } else if constexpr (EPI == 1) {
          uint16_t hb, lb;
          split2(vv, hb, lb);
          char* p = outb + (size_t)(row + j) * 2048 + (col >> 3) * 32 + (col & 7) * 2;
          *(uint16_t*)p = hb;
          *(uint16_t*)(p + 16) = lb;
        } else {
          ((bf16*)outb)[(size_t)(row + j) * 512 + col] = __float2bfloat16(vv);
        }
      }
    }
  }
}

// ---------------- final plain GEMM: out[M,256] = h_hi @ Wb.T + bb ----------------
__global__ __launch_bounds__(256) void gemm_final(const char* __restrict__ Aio,
                                                  const bf16* __restrict__ Wb,
                                                  const float* __restrict__ bias,
                                                  float* __restrict__ out) {
  __shared__ __align__(16) char lds[32768];  // 2 bufs x (A 8KB | B 8KB)
  const int tid = threadIdx.x, w = tid >> 6, l = tid & 63;
  const int bn = blockIdx.x * 128, bm = blockIdx.y * 128;

  const int srow = l >> 2;
  const int ss = (l & 3) ^ (srow & 3);
  const char* Asrc = Aio + (size_t)(bm + srow) * 2048 + ss * 32;  // hi chunks @32B stride
  const char* Bsrc = (const char*)Wb + (size_t)(bn + srow) * 1024 + ss * 16;

  const int lrow = l & 15, lk = l >> 4;
  const int wr = w >> 1, wc = w & 1;
  const int abase = (wr * 64 + lrow) * 64;
  const int bbase = 8192 + (wc * 64 + lrow) * 64;
  const int sf = (lk ^ (lrow & 3)) * 16;

  f32x4 acc[4][4] = {};
  auto stage = [&](int buf, int t) {
#pragma unroll
    for (int c = 0; c < 2; ++c) {
      const int i = w * 2 + c;
      gload16(Asrc + (size_t)i * 16 * 2048 + (size_t)t * 128, lds + buf * 16384 + i * 1024);
      gload16(Bsrc + (size_t)i * 16 * 1024 + (size_t)t * 64, lds + buf * 16384 + 8192 + i * 1024);
    }
  };
  stage(0, 0);
  __syncthreads();
  int cur = 0;
  for (int t = 0; t < 16; ++t) {
    if (t < 15) stage(cur ^ 1, t + 1);
    const char* bp = lds + cur * 16384;
    short8 af[4], bf_[4];
#pragma unroll
    for (int i = 0; i < 4; ++i) {
      af[i] = *(const short8*)(bp + abase + i * 1024 + sf);
      bf_[i] = *(const short8*)(bp + bbase + i * 1024 + sf);
    }
#pragma unroll
    for (int mi = 0; mi < 4; ++mi)
#pragma unroll
      for (int ni = 0; ni < 4; ++ni)
        acc[mi][ni] = __builtin_amdgcn_mfma_f32_16x16x32_bf16(af[mi], bf_[ni], acc[mi][ni], 0, 0, 0);
    __syncthreads();
    cur ^= 1;
  }
#pragma unroll
  for (int mi = 0; mi < 4; ++mi) {
    const int row = bm + wr * 64 + mi * 16 + lk * 4;
#pragma unroll
    for (int ni = 0; ni < 4; ++ni) {
      const int col = bn + wc * 64 + ni * 16 + lrow;
      const float bc = bias[col];
#pragma unroll
      for (int j = 0; j < 4; ++j)
        out[(size_t)(row + j) * 256 + col] = acc[mi][ni][j] + bc;
    }
  }
}

// ---------------- BN stats on io-format h ----------------
__global__ __launch_bounds__(256) void stats_io(const char* __restrict__ Hio,
                                                float* __restrict__ part) {
  __shared__ float sm[4096];
  const int t = threadIdx.x;
  const int chunk = t & 63, grp = t >> 6;
  const int r0 = blockIdx.x * 448 + grp * 112;
  float s[8] = {}, q[8] = {};
  for (int r = r0; r < r0 + 112; ++r) {
    const char* p = Hio + (size_t)r * 2048 + chunk * 32;
    uint4 hh = *(const uint4*)p, hl = *(const uint4*)(p + 16);
#pragma unroll
    for (int e = 0; e < 8; ++e) {
      float v = h16(hh, e) + h16(hl, e);
      s[e] += v;
      q[e] += v * v;
    }
  }
#pragma unroll
  for (int e = 0; e < 8; ++e) {
    sm[grp * 512 + chunk * 8 + e] = s[e];
    sm[2048 + grp * 512 + chunk * 8 + e] = q[e];
  }
  __syncthreads();
  float* pb = part + (size_t)blockIdx.x * 1024;
#pragma unroll
  for (int cc = 0; cc < 2; ++cc) {
    const int c = t * 2 + cc;
    float ssum = sm[c] + sm[512 + c] + sm[1024 + c] + sm[1536 + c];
    float qsum = sm[2048 + c] + sm[2560 + c] + sm[3072 + c] + sm[3584 + c];
    pb[c] = ssum;
    pb[512 + c] = qsum;
  }
}

__global__ __launch_bounds__(64) void reduce_stats(const float* __restrict__ part,
                                                   const float* __restrict__ g,
                                                   const float* __restrict__ bb,
                                                   float* __restrict__ sv,
                                                   float* __restrict__ tv) {
  const int c = blockIdx.x, k = threadIdx.x;
  float sum = 0.f, sq = 0.f;
#pragma unroll
  for (int j = 0; j < 4; ++j) {
    const float* p = part + (size_t)(k + 64 * j) * 1024;
    sum += p[c];
    sq += p[512 + c];
  }
#pragma unroll
  for (int o = 32; o; o >>= 1) {
    sum += __shfl_xor(sum, o);
    sq += __shfl_xor(sq, o);
  }
  if (k == 0) {
    const float mean = sum * (1.0f / 114688.0f);
    const float var = sq * (1.0f / 114688.0f) - mean * mean;
    const float sc = g[c] * rsqrtf(var + 1e-5f);
    sv[c] = sc;
    tv[c] = bb[c] - mean * sc;
  }
}

// ---------------- fused attention + residual + relu, in place on h ----------------
__global__ __launch_bounds__(256) void attn_relu(const float* __restrict__ qkf,
                                                 const bf16* __restrict__ V,
                                                 char* __restrict__ Hio,
                                                 const float* __restrict__ sv,
                                                 const float* __restrict__ tv) {
  const int w = threadIdx.x >> 6, l = threadIdx.x & 63;
  const int b = blockIdx.x * 4 + w;
  const size_t base = (size_t)b * 7;

  float qv[7], kv[7];
#pragma unroll
  for (int i = 0; i < 7; ++i) {
    qv[i] = qkf[(base + i) * 128 + l];
    kv[i] = qkf[(base + i) * 128 + 64 + l];
  }
  float att[7][7];
#pragma unroll
  for (int i = 0; i < 7; ++i)
#pragma unroll
    for (int j = 0; j < 7; ++j) {
      float p = qv[i] * kv[j];
#pragma unroll
      for (int o = 32; o; o >>= 1) p += __shfl_xor(p, o);
      att[i][j] = p;
    }
#pragma unroll
  for (int i = 0; i < 7; ++i) {
    float m = att[i][0];
#pragma unroll
    for (int j = 1; j < 7; ++j) m = fmaxf(m, att[i][j]);
    float sum = 0.f;
#pragma unroll
    for (int j = 0; j < 7; ++j) {
      att[i][j] = expf(att[i][j] - m);
      sum += att[i][j];
    }
    const float inv = 1.0f / sum;
#pragma unroll
    for (int j = 0; j < 7; ++j) att[i][j] *= inv;
  }

  const float4 s0 = *(const float4*)&sv[l * 8], s1 = *(const float4*)&sv[l * 8 + 4];
  const float4 t0 = *(const float4*)&tv[l * 8], t1 = *(const float4*)&tv[l * 8 + 4];
  const float sarr[8] = {s0.x, s0.y, s0.z, s0.w, s1.x, s1.y, s1.z, s1.w};
  const float tarr[8] = {t0.x, t0.y, t0.z, t0.w, t1.x, t1.y, t1.z, t1.w};

  uint4 vpk[7];
#pragma unroll
  for (int j = 0; j < 7; ++j)
    vpk[j] = *(const uint4*)((const char*)V + (base + j) * 1024 + l * 16);

#pragma unroll
  for (int i = 0; i < 7; ++i) {
    char* hp = Hio + (base + i) * 2048 + l * 32;
    uint4 hh = *(const uint4*)hp;
    uint4 hl = *(const uint4*)(hp + 16);
    float o[8] = {};
#pragma unroll
    for (int j = 0; j < 7; ++j) {
      const float a = att[i][j];
#pragma unroll
      for (int e = 0; e < 8; ++e) o[e] += a * h16(vpk[j], e);
    }
    uint16_t oh[8], ol[8];
#pragma unroll
    for (int e = 0; e < 8; ++e) {
      const float hval = h16(hh, e) + h16(hl, e);
      const float r = fmaxf(o[e] + hval * sarr[e] + tarr[e], 0.f);
      split2(r, oh[e], ol[e]);
    }
    uint4 ph, pl;
#pragma unroll
    for (int k2 = 0; k2 < 4; ++k2) {
      ((uint32_t*)&ph)[k2] = (uint32_t)oh[2 * k2] | ((uint32_t)oh[2 * k2 + 1] << 16);
      ((uint32_t*)&pl)[k2] = (uint32_t)ol[2 * k2] | ((uint32_t)ol[2 * k2 + 1] << 16);
    }
    *(uint4*)hp = ph;
    *(uint4*)(hp + 16) = pl;
  }
}

extern "C" void kernel_launch(void* const* d_in, const int* in_sizes, int n_in,
                              void* d_out, int out_size, void* d_ws, size_t ws_size,
                              hipStream_t stream) {
  const float* x  = (const float*)d_in[0];
  const float* Wt = (const float*)d_in[1];
  const float* bt = (const float*)d_in[2];
  const float *bng[3], *bnb[3], *Wq[3], *bq[3], *Wk[3], *bk[3], *Wv[3], *bv[3], *gam[3];
  for (int i = 0; i < 3; ++i) {
    int o = 3 + 9 * i;
    bng[i] = (const float*)d_in[o + 0];
    bnb[i] = (const float*)d_in[o + 1];
    Wq[i]  = (const float*)d_in[o + 2];
    bq[i]  = (const float*)d_in[o + 3];
    Wk[i]  = (const float*)d_in[o + 4];
    bk[i]  = (const float*)d_in[o + 5];
    Wv[i]  = (const float*)d_in[o + 6];
    bv[i]  = (const float*)d_in[o + 7];
    gam[i] = (const float*)d_in[o + 8];
  }
  const float* Wb = (const float*)d_in[30];
  const float* bb = (const float*)d_in[31];

  char* ws = (char*)d_ws;
  char*  Hio   = ws;                               // 235,929,600 (114688 x 2048B)
  char*  V     = ws + 235929600;                   // 117,440,512 (plain bf16)
  float* part  = (float*)(ws + 353370112);         // 1,048,576
  float* sv    = (float*)(ws + 354418688);         // 2,048
  float* tv    = (float*)(ws + 354420736);         // 2,048
  char*  WqkIo = ws + 354422784;                   // 262,144 (128 rows io)
  float* bqkf  = (float*)(ws + 354684928);         // 2,048
  char*  WvIo  = ws + 354686976;                   // 1,048,576 (512 rows io)
  float* bvf   = (float*)(ws + 355735552);         // 2,048
  char*  WtIo  = ws + 355737600;                   // 1,048,576
  float* btf   = (float*)(ws + 356786176);         // 2,048
  bf16*  Wbbf  = (bf16*)(ws + 356788224);          // 262,144
  float* qkf   = (float*)d_out;                    // 58,720,256 <= out bytes (117MB)

  // weight prep
  cvt4<<<128, 256, 0, stream>>>(Wb, Wbbf, 32768);
  fold_w_io<<<512, 512, 0, stream>>>(Wt, bt, nullptr, nullptr, nullptr, WtIo, btf);

  // h0 = x @ Wt.T + bt   (A = f32 x, split in-register; io out)
  sgemm256<1, 1, 256><<<dim3(2, 448), 512, 0, stream>>>((const char*)x, WtIo, btf,
                                                        nullptr, Hio, 512);

  for (int i = 0; i < 3; ++i) {
    stats_io<<<256, 256, 0, stream>>>(Hio, part);
    reduce_stats<<<512, 64, 0, stream>>>(part, bng[i], bnb[i], sv, tv);
    fold_w_io<<<64, 512, 0, stream>>>(Wq[i], bq[i], sv, tv, nullptr, WqkIo, bqkf);
    fold_w_io<<<64, 512, 0, stream>>>(Wk[i], bk[i], sv, tv, nullptr,
                                      WqkIo + (size_t)64 * 2048, bqkf + 64);
    fold_w_io<<<512, 512, 0, stream>>>(Wv[i], bv[i], sv, tv, gam[i], WvIo, bvf);
    // q|k = h @ Wqk'.T + b'  (f32 out on d_out)
    sgemm256<0, 0, 128><<<dim3(1, 448), 512, 0, stream>>>(Hio, WqkIo, bqkf, qkf, nullptr, 128);
    // v' = h @ (gam*Wv*s)'.T + b''  (plain bf16 out)
    sgemm256<0, 2, 256><<<dim3(2, 448), 512, 0, stream>>>(Hio, WvIo, bvf, nullptr, V, 512);
    // h = relu(att@v' + h*s + t)  in place
    attn_relu<<<4096, 256, 0, stream>>>(qkf, (const bf16*)V, Hio, sv, tv);
  }

  // out = h3_hi @ Wb.T + bb
  gemm_final<<<dim3(2, 896), 256, 0, stream>>>(Hio, Wbbf, bb, (float*)d_out);
}

// Round 5
// 1746.547 us; speedup vs baseline: 1.0001x; 1.0001x over previous
//
#include <hip/hip_runtime.h>
#include <hip/hip_bf16.h>
#include <stdint.h>

// LevelReasoning on MI355X — round 5: chain-broken split MFMA.
// Identical to round 4 except the sgemm256 inner MFMA cluster is pass-major
// (hh*8, hl*8, lh*8) so consecutive MFMAs hit independent accumulators —
// breaking the 3-deep dependent accumulate chain that capped issue at ~1/3.

using bf16 = __hip_bfloat16;
typedef __attribute__((ext_vector_type(8))) short short8;
typedef __attribute__((ext_vector_type(4))) float f32x4;

__device__ inline uint16_t f2b_bits(float f) {
  bf16 h = __float2bfloat16(f);
  return __builtin_bit_cast(uint16_t, h);
}
__device__ inline float b2f_bits(uint16_t u) { return __uint_as_float(((uint32_t)u) << 16); }
__device__ inline float bflo(uint32_t u) { return __uint_as_float((u & 0xffffu) << 16); }
__device__ inline float bfhi(uint32_t u) { return __uint_as_float(u & 0xffff0000u); }
__device__ inline void split2(float v, uint16_t& hi, uint16_t& lo) {
  hi = f2b_bits(v);
  lo = f2b_bits(v - b2f_bits(hi));
}
__device__ inline float h16(const uint4& u, int e) {
  uint32_t wrd = ((const uint32_t*)&u)[e >> 1];
  return (e & 1) ? bfhi(wrd) : bflo(wrd);
}

typedef const __attribute__((address_space(1))) void* gas_ptr;
typedef __attribute__((address_space(3))) void* las_ptr;
__device__ inline void gload16(const void* g, void* l) {
  __builtin_amdgcn_global_load_lds((gas_ptr)g, (las_ptr)l, 16, 0, 0);
}

// ---------------- f32 -> bf16 (plain, for Wb) ----------------
__global__ __launch_bounds__(256) void cvt4(const float* __restrict__ in,
                                            bf16* __restrict__ out, int n4) {
  int i = blockIdx.x * 256 + threadIdx.x;
  const int stride = gridDim.x * 256;
  for (; i < n4; i += stride) {
    float4 v = ((const float4*)in)[i];
    uint32_t lo = (uint32_t)f2b_bits(v.x) | ((uint32_t)f2b_bits(v.y) << 16);
    uint32_t hi = (uint32_t)f2b_bits(v.z) | ((uint32_t)f2b_bits(v.w) << 16);
    ((uint2*)out)[i] = make_uint2(lo, hi);
  }
}

// ---------------- fold weight to io-format: W' = g*W*diag(s), b' = g*(b + t@W.T) ----------------
__global__ __launch_bounds__(512) void fold_w_io(const float* __restrict__ Wsrc,
                                                 const float* __restrict__ bsrc,
                                                 const float* __restrict__ sv,
                                                 const float* __restrict__ tv,
                                                 const float* __restrict__ gamp,
                                                 char* __restrict__ Wio,
                                                 float* __restrict__ bout) {
  const int row = blockIdx.x, c = threadIdx.x;
  __shared__ float red[512];
  const float wv = Wsrc[(size_t)row * 512 + c];
  const float g = gamp ? gamp[0] : 1.0f;
  const float s = sv ? sv[c] : 1.0f;
  uint16_t hb, lb;
  split2(g * wv * s, hb, lb);
  char* p = Wio + (size_t)row * 2048 + (c >> 3) * 32 + (c & 7) * 2;
  *(uint16_t*)p = hb;
  *(uint16_t*)(p + 16) = lb;
  red[c] = tv ? wv * tv[c] : 0.0f;
  __syncthreads();
#pragma unroll
  for (int off = 256; off > 0; off >>= 1) {
    if (c < off) red[c] += red[c + off];
    __syncthreads();
  }
  if (c == 0) bout[row] = g * (bsrc[row] + red[0]);
}

// ---------------- 256-tile split GEMM, 8 waves, counted vmcnt ----------------
// AMODE 0: A = io-format split bf16 (2KB rows). AMODE 1: A = f32 (2KB rows), split in-reg.
// EPI 0: outf[row*N+col]=acc+bias. EPI 1: io-format out. EPI 2: plain bf16, pitch 512.
template <int AMODE, int EPI, int BN>
__global__ __launch_bounds__(512, 1) void sgemm256(const char* __restrict__ A,
                                                   const char* __restrict__ Wio,
                                                   const float* __restrict__ bias,
                                                   float* __restrict__ outf,
                                                   char* __restrict__ outb, int N) {
  constexpr int NFR = BN / 64;      // B frags per wave (n dir)
  constexpr int BCH = BN / 64;      // B 1KB-chunks per wave per tile
  constexpr int PER_BUF = 32768 + BN * 128;
  __shared__ __align__(16) char lds[2 * PER_BUF];
  const int tid = threadIdx.x, w = tid >> 6, l = tid & 63;

  // XCD-chunked bijective block swizzle (nwg % 8 == 0 for all our grids)
  const int nwgx = gridDim.x;
  const int raw = blockIdx.y * nwgx + blockIdx.x;
  const int cpx = (nwgx * gridDim.y) >> 3;
  const int work = (raw & 7) * cpx + (raw >> 3);
  const int bm = (work / nwgx) * 256;
  const int bn = (work % nwgx) * BN;

  // staging lane geometry: lane l covers row (base + l>>3), swizzled 32B slot+16B piece
  const int ssl = ((((l >> 1) & 3) ^ ((l >> 3) & 3)) << 5) | (((l & 1) ^ ((l >> 5) & 1)) << 4);
  const char* Asrc = A + (size_t)(bm + w * 32 + (l >> 3)) * 2048 + ssl;
  const char* Bsrc = Wio + (size_t)(bn + w * (BCH * 8) + (l >> 3)) * 2048 + ssl;

  // fragment-read geometry
  const int lrow = l & 15, lk = l >> 4;
  const int wr = w >> 2, wc = w & 3;  // 2x4 wave grid; wave tile 128 x (BN/4)
  const int sw32 = (lk ^ (lrow & 3)) * 32;
  const int hi16 = ((lrow >> 2) & 1) * 16;
  const int afr = (wr * 128 + lrow) * 128 + sw32;               // + mi*2048 (+hi16/lo)
  const int bfr = 32768 + (wc * (BN / 4) + lrow) * 128 + sw32;  // + ni*2048

  f32x4 acc[8][NFR] = {};

  auto stage = [&](int buf, int t) {
    char* ab = lds + buf * PER_BUF + w * 4096;
    const char* as = Asrc + (size_t)t * 128;
#pragma unroll
    for (int k = 0; k < 4; ++k) gload16(as + (size_t)k * 16384, ab + k * 1024);
    char* bbf = lds + buf * PER_BUF + 32768 + w * (BCH * 1024);
    const char* bs = Bsrc + (size_t)t * 128;
#pragma unroll
    for (int k = 0; k < BCH; ++k) gload16(bs + (size_t)k * 16384, bbf + k * 1024);
  };

  stage(0, 0);
  int cur = 0;
  for (int t = 0; t < 16; ++t) {
    if (t < 15) {
      stage(cur ^ 1, t + 1);  // keep next tile in flight across all barriers
      if constexpr (BN == 256) {
        asm volatile("s_waitcnt vmcnt(8)" ::: "memory");
      } else {
        asm volatile("s_waitcnt vmcnt(6)" ::: "memory");
      }
    } else {
      asm volatile("s_waitcnt vmcnt(0)" ::: "memory");
    }
    __builtin_amdgcn_s_barrier();  // tile t visible to all waves
    asm volatile("" ::: "memory");

    const char* bp = lds + cur * PER_BUF;
    short8 bh[NFR], bl[NFR];
#pragma unroll
    for (int ni = 0; ni < NFR; ++ni) {
      bh[ni] = *(const short8*)(bp + bfr + ni * 2048 + hi16);
      bl[ni] = *(const short8*)(bp + bfr + ni * 2048 + (hi16 ^ 16));
    }
#pragma unroll
    for (int q = 0; q < 4; ++q) {
      short8 ah[2], al[2];
#pragma unroll
      for (int u = 0; u < 2; ++u) {
        const int mi = q * 2 + u;
        if constexpr (AMODE == 0) {
          ah[u] = *(const short8*)(bp + afr + mi * 2048 + hi16);
          al[u] = *(const short8*)(bp + afr + mi * 2048 + (hi16 ^ 16));
        } else {
          float4 f0 = *(const float4*)(bp + afr + mi * 2048 + hi16);
          float4 f1 = *(const float4*)(bp + afr + mi * 2048 + (hi16 ^ 16));
          const float fv[8] = {f0.x, f0.y, f0.z, f0.w, f1.x, f1.y, f1.z, f1.w};
#pragma unroll
          for (int e = 0; e < 8; ++e) {
            uint16_t hb, lb;
            split2(fv[e], hb, lb);
            ah[u][e] = (short)hb;
            al[u][e] = (short)lb;
          }
        }
      }
      __builtin_amdgcn_s_barrier();
      asm volatile("" ::: "memory");
      __builtin_amdgcn_s_setprio(1);
      // pass-major: consecutive MFMAs hit independent accumulators.
      // per-acc order stays hh -> hl -> lh (numerics identical to r4).
#pragma unroll
      for (int u = 0; u < 2; ++u)
#pragma unroll
        for (int ni = 0; ni < NFR; ++ni) {
          f32x4& a = acc[q * 2 + u][ni];
          a = __builtin_amdgcn_mfma_f32_16x16x32_bf16(ah[u], bh[ni], a, 0, 0, 0);
        }
#pragma unroll
      for (int u = 0; u < 2; ++u)
#pragma unroll
        for (int ni = 0; ni < NFR; ++ni) {
          f32x4& a = acc[q * 2 + u][ni];
          a = __builtin_amdgcn_mfma_f32_16x16x32_bf16(ah[u], bl[ni], a, 0, 0, 0);
        }
#pragma unroll
      for (int u = 0; u < 2; ++u)
#pragma unroll
        for (int ni = 0; ni < NFR; ++ni) {
          f32x4& a = acc[q * 2 + u][ni];
          a = __builtin_amdgcn_mfma_f32_16x16x32_bf16(al[u], bh[ni], a, 0, 0, 0);
        }
      __builtin_amdgcn_s_setprio(0);
      __builtin_amdgcn_s_barrier();
      asm volatile("" ::: "memory");
    }
    cur ^= 1;
  }

#pragma unroll
  for (int mi = 0; mi < 8; ++mi) {
    const int row = bm + wr * 128 + mi * 16 + lk * 4;
#pragma unroll
    for (int ni = 0; ni < NFR; ++ni) {
      const int col = bn + wc * (BN / 4) + ni * 16 + lrow;
      const float bc = bias[col];
#pragma unroll
      for (int j = 0; j < 4; ++j) {
        const float vv = acc[mi][ni][j] + bc;
        if constexpr (EPI == 0) {
          outf[(size_t)(row + j) * N + col] = vv;
        } else if constexpr (EPI == 1) {
          uint16_t hb, lb;
          split2(vv, hb, lb);
          char* p = outb + (size_t)(row + j) * 2048 + (col >> 3) * 32 + (col & 7) * 2;
          *(uint16_t*)p = hb;
          *(uint16_t*)(p + 16) = lb;
        } else {
          ((bf16*)outb)[(size_t)(row + j) * 512 + col] = __float2bfloat16(vv);
        }
      }
    }
  }
}

// ---------------- final plain GEMM: out[M,256] = h_hi @ Wb.T + bb ----------------
__global__ __launch_bounds__(256) void gemm_final(const char* __restrict__ Aio,
                                                  const bf16* __restrict__ Wb,
                                                  const float* __restrict__ bias,
                                                  float* __restrict__ out) {
  __shared__ __align__(16) char lds[32768];  // 2 bufs x (A 8KB | B 8KB)
  const int tid = threadIdx.x, w = tid >> 6, l = tid & 63;
  const int bn = blockIdx.x * 128, bm = blockIdx.y * 128;

  const int srow = l >> 2;
  const int ss = (l & 3) ^ (srow & 3);
  const char* Asrc = Aio + (size_t)(bm + srow) * 2048 + ss * 32;  // hi chunks @32B stride
  const char* Bsrc = (const char*)Wb + (size_t)(bn + srow) * 1024 + ss * 16;

  const int lrow = l & 15, lk = l >> 4;
  const int wr = w >> 1, wc = w & 1;
  const int abase = (wr * 64 + lrow) * 64;
  const int bbase = 8192 + (wc * 64 + lrow) * 64;
  const int sf = (lk ^ (lrow & 3)) * 16;

  f32x4 acc[4][4] = {};
  auto stage = [&](int buf, int t) {
#pragma unroll
    for (int c = 0; c < 2; ++c) {
      const int i = w * 2 + c;
      gload16(Asrc + (size_t)i * 16 * 2048 + (size_t)t * 128, lds + buf * 16384 + i * 1024);
      gload16(Bsrc + (size_t)i * 16 * 1024 + (size_t)t * 64, lds + buf * 16384 + 8192 + i * 1024);
    }
  };
  stage(0, 0);
  __syncthreads();
  int cur = 0;
  for (int t = 0; t < 16; ++t) {
    if (t < 15) stage(cur ^ 1, t + 1);
    const char* bp = lds + cur * 16384;
    short8 af[4], bf_[4];
#pragma unroll
    for (int i = 0; i < 4; ++i) {
      af[i] = *(const short8*)(bp + abase + i * 1024 + sf);
      bf_[i] = *(const short8*)(bp + bbase + i * 1024 + sf);
    }
#pragma unroll
    for (int mi = 0; mi < 4; ++mi)
#pragma unroll
      for (int ni = 0; ni < 4; ++ni)
        acc[mi][ni] = __builtin_amdgcn_mfma_f32_16x16x32_bf16(af[mi], bf_[ni], acc[mi][ni], 0, 0, 0);
    __syncthreads();
    cur ^= 1;
  }
#pragma unroll
  for (int mi = 0; mi < 4; ++mi) {
    const int row = bm + wr * 64 + mi * 16 + lk * 4;
#pragma unroll
    for (int ni = 0; ni < 4; ++ni) {
      const int col = bn + wc * 64 + ni * 16 + lrow;
      const float bc = bias[col];
#pragma unroll
      for (int j = 0; j < 4; ++j)
        out[(size_t)(row + j) * 256 + col] = acc[mi][ni][j] + bc;
    }
  }
}

// ---------------- BN stats on io-format h ----------------
__global__ __launch_bounds__(256) void stats_io(const char* __restrict__ Hio,
                                                float* __restrict__ part) {
  __shared__ float sm[4096];
  const int t = threadIdx.x;
  const int chunk = t & 63, grp = t >> 6;
  const int r0 = blockIdx.x * 448 + grp * 112;
  float s[8] = {}, q[8] = {};
  for (int r = r0; r < r0 + 112; ++r) {
    const char* p = Hio + (size_t)r * 2048 + chunk * 32;
    uint4 hh = *(const uint4*)p, hl = *(const uint4*)(p + 16);
#pragma unroll
    for (int e = 0; e < 8; ++e) {
      float v = h16(hh, e) + h16(hl, e);
      s[e] += v;
      q[e] += v * v;
    }
  }
#pragma unroll
  for (int e = 0; e < 8; ++e) {
    sm[grp * 512 + chunk * 8 + e] = s[e];
    sm[2048 + grp * 512 + chunk * 8 + e] = q[e];
  }
  __syncthreads();
  float* pb = part + (size_t)blockIdx.x * 1024;
#pragma unroll
  for (int cc = 0; cc < 2; ++cc) {
    const int c = t * 2 + cc;
    float ssum = sm[c] + sm[512 + c] + sm[1024 + c] + sm[1536 + c];
    float qsum = sm[2048 + c] + sm[2560 + c] + sm[3072 + c] + sm[3584 + c];
    pb[c] = ssum;
    pb[512 + c] = qsum;
  }
}

__global__ __launch_bounds__(64) void reduce_stats(const float* __restrict__ part,
                                                   const float* __restrict__ g,
                                                   const float* __restrict__ bb,
                                                   float* __restrict__ sv,
                                                   float* __restrict__ tv) {
  const int c = blockIdx.x, k = threadIdx.x;
  float sum = 0.f, sq = 0.f;
#pragma unroll
  for (int j = 0; j < 4; ++j) {
    const float* p = part + (size_t)(k + 64 * j) * 1024;
    sum += p[c];
    sq += p[512 + c];
  }
#pragma unroll
  for (int o = 32; o; o >>= 1) {
    sum += __shfl_xor(sum, o);
    sq += __shfl_xor(sq, o);
  }
  if (k == 0) {
    const float mean = sum * (1.0f / 114688.0f);
    const float var = sq * (1.0f / 114688.0f) - mean * mean;
    const float sc = g[c] * rsqrtf(var + 1e-5f);
    sv[c] = sc;
    tv[c] = bb[c] - mean * sc;
  }
}

// ---------------- fused attention + residual + relu, in place on h ----------------
__global__ __launch_bounds__(256) void attn_relu(const float* __restrict__ qkf,
                                                 const bf16* __restrict__ V,
                                                 char* __restrict__ Hio,
                                                 const float* __restrict__ sv,
                                                 const float* __restrict__ tv) {
  const int w = threadIdx.x >> 6, l = threadIdx.x & 63;
  const int b = blockIdx.x * 4 + w;
  const size_t base = (size_t)b * 7;

  float qv[7], kv[7];
#pragma unroll
  for (int i = 0; i < 7; ++i) {
    qv[i] = qkf[(base + i) * 128 + l];
    kv[i] = qkf[(base + i) * 128 + 64 + l];
  }
  float att[7][7];
#pragma unroll
  for (int i = 0; i < 7; ++i)
#pragma unroll
    for (int j = 0; j < 7; ++j) {
      float p = qv[i] * kv[j];
#pragma unroll
      for (int o = 32; o; o >>= 1) p += __shfl_xor(p, o);
      att[i][j] = p;
    }
#pragma unroll
  for (int i = 0; i < 7; ++i) {
    float m = att[i][0];
#pragma unroll
    for (int j = 1; j < 7; ++j) m = fmaxf(m, att[i][j]);
    float sum = 0.f;
#pragma unroll
    for (int j = 0; j < 7; ++j) {
      att[i][j] = expf(att[i][j] - m);
      sum += att[i][j];
    }
    const float inv = 1.0f / sum;
#pragma unroll
    for (int j = 0; j < 7; ++j) att[i][j] *= inv;
  }

  const float4 s0 = *(const float4*)&sv[l * 8], s1 = *(const float4*)&sv[l * 8 + 4];
  const float4 t0 = *(const float4*)&tv[l * 8], t1 = *(const float4*)&tv[l * 8 + 4];
  const float sarr[8] = {s0.x, s0.y, s0.z, s0.w, s1.x, s1.y, s1.z, s1.w};
  const float tarr[8] = {t0.x, t0.y, t0.z, t0.w, t1.x, t1.y, t1.z, t1.w};

  uint4 vpk[7];
#pragma unroll
  for (int j = 0; j < 7; ++j)
    vpk[j] = *(const uint4*)((const char*)V + (base + j) * 1024 + l * 16);

#pragma unroll
  for (int i = 0; i < 7; ++i) {
    char* hp = Hio + (base + i) * 2048 + l * 32;
    uint4 hh = *(const uint4*)hp;
    uint4 hl = *(const uint4*)(hp + 16);
    float o[8] = {};
#pragma unroll
    for (int j = 0; j < 7; ++j) {
      const float a = att[i][j];
#pragma unroll
      for (int e = 0; e < 8; ++e) o[e] += a * h16(vpk[j], e);
    }
    uint16_t oh[8], ol[8];
#pragma unroll
    for (int e = 0; e < 8; ++e) {
      const float hval = h16(hh, e) + h16(hl, e);
      const float r = fmaxf(o[e] + hval * sarr[e] + tarr[e], 0.f);
      split2(r, oh[e], ol[e]);
    }
    uint4 ph, pl;
#pragma unroll
    for (int k2 = 0; k2 < 4; ++k2) {
      ((uint32_t*)&ph)[k2] = (uint32_t)oh[2 * k2] | ((uint32_t)oh[2 * k2 + 1] << 16);
      ((uint32_t*)&pl)[k2] = (uint32_t)ol[2 * k2] | ((uint32_t)ol[2 * k2 + 1] << 16);
    }
    *(uint4*)hp = ph;
    *(uint4*)(hp + 16) = pl;
  }
}

extern "C" void kernel_launch(void* const* d_in, const int* in_sizes, int n_in,
                              void* d_out, int out_size, void* d_ws, size_t ws_size,
                              hipStream_t stream) {
  const float* x  = (const float*)d_in[0];
  const float* Wt = (const float*)d_in[1];
  const float* bt = (const float*)d_in[2];
  const float *bng[3], *bnb[3], *Wq[3], *bq[3], *Wk[3], *bk[3], *Wv[3], *bv[3], *gam[3];
  for (int i = 0; i < 3; ++i) {
    int o = 3 + 9 * i;
    bng[i] = (const float*)d_in[o + 0];
    bnb[i] = (const float*)d_in[o + 1];
    Wq[i]  = (const float*)d_in[o + 2];
    bq[i]  = (const float*)d_in[o + 3];
    Wk[i]  = (const float*)d_in[o + 4];
    bk[i]  = (const float*)d_in[o + 5];
    Wv[i]  = (const float*)d_in[o + 6];
    bv[i]  = (const float*)d_in[o + 7];
    gam[i] = (const float*)d_in[o + 8];
  }
  const float* Wb = (const float*)d_in[30];
  const float* bb = (const float*)d_in[31];

  char* ws = (char*)d_ws;
  char*  Hio   = ws;                               // 235,929,600 (114688 x 2048B)
  char*  V     = ws + 235929600;                   // 117,440,512 (plain bf16)
  float* part  = (float*)(ws + 353370112);         // 1,048,576
  float* sv    = (float*)(ws + 354418688);         // 2,048
  float* tv    = (float*)(ws + 354420736);         // 2,048
  char*  WqkIo = ws + 354422784;                   // 262,144 (128 rows io)
  float* bqkf  = (float*)(ws + 354684928);         // 2,048
  char*  WvIo  = ws + 354686976;                   // 1,048,576 (512 rows io)
  float* bvf   = (float*)(ws + 355735552);         // 2,048
  char*  WtIo  = ws + 355737600;                   // 1,048,576
  float* btf   = (float*)(ws + 356786176);         // 2,048
  bf16*  Wbbf  = (bf16*)(ws + 356788224);          // 262,144
  float* qkf   = (float*)d_out;                    // 58,720,256 <= out bytes (117MB)

  // weight prep
  cvt4<<<128, 256, 0, stream>>>(Wb, Wbbf, 32768);
  fold_w_io<<<512, 512, 0, stream>>>(Wt, bt, nullptr, nullptr, nullptr, WtIo, btf);

  // h0 = x @ Wt.T + bt   (A = f32 x, split in-register; io out)
  sgemm256<1, 1, 256><<<dim3(2, 448), 512, 0, stream>>>((const char*)x, WtIo, btf,
                                                        nullptr, Hio, 512);

  for (int i = 0; i < 3; ++i) {
    stats_io<<<256, 256, 0, stream>>>(Hio, part);
    reduce_stats<<<512, 64, 0, stream>>>(part, bng[i], bnb[i], sv, tv);
    fold_w_io<<<64, 512, 0, stream>>>(Wq[i], bq[i], sv, tv, nullptr, WqkIo, bqkf);
    fold_w_io<<<64, 512, 0, stream>>>(Wk[i], bk[i], sv, tv, nullptr,
                                      WqkIo + (size_t)64 * 2048, bqkf + 64);
    fold_w_io<<<512, 512, 0, stream>>>(Wv[i], bv[i], sv, tv, gam[i], WvIo, bvf);
    // q|k = h @ Wqk'.T + b'  (f32 out on d_out)
    sgemm256<0, 0, 128><<<dim3(1, 448), 512, 0, stream>>>(Hio, WqkIo, bqkf, qkf, nullptr, 128);
    // v' = h @ (gam*Wv*s)'.T + b''  (plain bf16 out)
    sgemm256<0, 2, 256><<<dim3(2, 448), 512, 0, stream>>>(Hio, WvIo, bvf, nullptr, V, 512);
    // h = relu(att@v' + h*s + t)  in place
    attn_relu<<<4096, 256, 0, stream>>>(qkf, (const bf16*)V, Hio, sv, tv);
  }

  // out = h3_hi @ Wb.T + bb
  gemm_final<<<dim3(2, 896), 256, 0, stream>>>(Hio, Wbbf, bb, (float*)d_out);
}

// Round 6
// 1653.483 us; speedup vs baseline: 1.0564x; 1.0563x over previous
//
#include <hip/hip_runtime.h>
#include <hip/hip_bf16.h>
#include <stdint.h>

// LevelReasoning on MI355X — round 6: single-barrier K-tile pipeline.
// sgemm256 restructured: ONE s_barrier + ONE vmcnt(0) per K-tile (was 9 barriers),
// stages distributed inside the tile (A after barrier, B between MFMA halves),
// two 48-MFMA clusters per tile, B-frags register-resident, compiler-counted lgkm.
// Hazards: RAW via per-wave vmcnt(0)+barrier at tile top; WAR via own-MFMA
// consumption before next barrier. Numerics identical to r4/r5.

using bf16 = __hip_bfloat16;
typedef __attribute__((ext_vector_type(8))) short short8;
typedef __attribute__((ext_vector_type(4))) float f32x4;

__device__ inline uint16_t f2b_bits(float f) {
  bf16 h = __float2bfloat16(f);
  return __builtin_bit_cast(uint16_t, h);
}
__device__ inline float b2f_bits(uint16_t u) { return __uint_as_float(((uint32_t)u) << 16); }
__device__ inline float bflo(uint32_t u) { return __uint_as_float((u & 0xffffu) << 16); }
__device__ inline float bfhi(uint32_t u) { return __uint_as_float(u & 0xffff0000u); }
__device__ inline void split2(float v, uint16_t& hi, uint16_t& lo) {
  hi = f2b_bits(v);
  lo = f2b_bits(v - b2f_bits(hi));
}
__device__ inline float h16(const uint4& u, int e) {
  uint32_t wrd = ((const uint32_t*)&u)[e >> 1];
  return (e & 1) ? bfhi(wrd) : bflo(wrd);
}

typedef const __attribute__((address_space(1))) void* gas_ptr;
typedef __attribute__((address_space(3))) void* las_ptr;
__device__ inline void gload16(const void* g, void* l) {
  __builtin_amdgcn_global_load_lds((gas_ptr)g, (las_ptr)l, 16, 0, 0);
}

// ---------------- f32 -> bf16 (plain, for Wb) ----------------
__global__ __launch_bounds__(256) void cvt4(const float* __restrict__ in,
                                            bf16* __restrict__ out, int n4) {
  int i = blockIdx.x * 256 + threadIdx.x;
  const int stride = gridDim.x * 256;
  for (; i < n4; i += stride) {
    float4 v = ((const float4*)in)[i];
    uint32_t lo = (uint32_t)f2b_bits(v.x) | ((uint32_t)f2b_bits(v.y) << 16);
    uint32_t hi = (uint32_t)f2b_bits(v.z) | ((uint32_t)f2b_bits(v.w) << 16);
    ((uint2*)out)[i] = make_uint2(lo, hi);
  }
}

// ---------------- fold weight to io-format: W' = g*W*diag(s), b' = g*(b + t@W.T) ----------------
__global__ __launch_bounds__(512) void fold_w_io(const float* __restrict__ Wsrc,
                                                 const float* __restrict__ bsrc,
                                                 const float* __restrict__ sv,
                                                 const float* __restrict__ tv,
                                                 const float* __restrict__ gamp,
                                                 char* __restrict__ Wio,
                                                 float* __restrict__ bout) {
  const int row = blockIdx.x, c = threadIdx.x;
  __shared__ float red[512];
  const float wv = Wsrc[(size_t)row * 512 + c];
  const float g = gamp ? gamp[0] : 1.0f;
  const float s = sv ? sv[c] : 1.0f;
  uint16_t hb, lb;
  split2(g * wv * s, hb, lb);
  char* p = Wio + (size_t)row * 2048 + (c >> 3) * 32 + (c & 7) * 2;
  *(uint16_t*)p = hb;
  *(uint16_t*)(p + 16) = lb;
  red[c] = tv ? wv * tv[c] : 0.0f;
  __syncthreads();
#pragma unroll
  for (int off = 256; off > 0; off >>= 1) {
    if (c < off) red[c] += red[c + off];
    __syncthreads();
  }
  if (c == 0) bout[row] = g * (bsrc[row] + red[0]);
}

// ---------------- 256-tile split GEMM, 8 waves, single barrier per K-tile ----------------
// AMODE 0: A = io-format split bf16 (2KB rows). AMODE 1: A = f32 (2KB rows), split in-reg.
// EPI 0: outf[row*N+col]=acc+bias. EPI 1: io-format out. EPI 2: plain bf16, pitch 512.
template <int AMODE, int EPI, int BN>
__global__ __launch_bounds__(512, 1) void sgemm256(const char* __restrict__ A,
                                                   const char* __restrict__ Wio,
                                                   const float* __restrict__ bias,
                                                   float* __restrict__ outf,
                                                   char* __restrict__ outb, int N) {
  constexpr int NFR = BN / 64;      // B frags per wave (n dir)
  constexpr int BCH = BN / 64;      // B 1KB-chunks per wave per tile
  constexpr int PER_BUF = 32768 + BN * 128;
  __shared__ __align__(16) char lds[2 * PER_BUF];
  const int tid = threadIdx.x, w = tid >> 6, l = tid & 63;

  // XCD-chunked bijective block swizzle (nwg % 8 == 0 for all our grids)
  const int nwgx = gridDim.x;
  const int raw = blockIdx.y * nwgx + blockIdx.x;
  const int cpx = (nwgx * gridDim.y) >> 3;
  const int work = (raw & 7) * cpx + (raw >> 3);
  const int bm = (work / nwgx) * 256;
  const int bn = (work % nwgx) * BN;

  // staging lane geometry: lane l covers row (base + l>>3), swizzled 32B slot+16B piece
  const int ssl = ((((l >> 1) & 3) ^ ((l >> 3) & 3)) << 5) | (((l & 1) ^ ((l >> 5) & 1)) << 4);
  const char* Asrc = A + (size_t)(bm + w * 32 + (l >> 3)) * 2048 + ssl;
  const char* Bsrc = Wio + (size_t)(bn + w * (BCH * 8) + (l >> 3)) * 2048 + ssl;

  // fragment-read geometry
  const int lrow = l & 15, lk = l >> 4;
  const int wr = w >> 2, wc = w & 3;  // 2x4 wave grid; wave tile 128 x (BN/4)
  const int sw32 = (lk ^ (lrow & 3)) * 32;
  const int hi16 = ((lrow >> 2) & 1) * 16;
  const int afr = (wr * 128 + lrow) * 128 + sw32;               // + mi*2048 (+hi16/lo)
  const int bfr = 32768 + (wc * (BN / 4) + lrow) * 128 + sw32;  // + ni*2048

  f32x4 acc[8][NFR] = {};

  auto stage_a = [&](int buf, int t) {
    char* ab = lds + buf * PER_BUF + w * 4096;
    const char* as = Asrc + (size_t)t * 128;
#pragma unroll
    for (int k = 0; k < 4; ++k) gload16(as + (size_t)k * 16384, ab + k * 1024);
  };
  auto stage_b = [&](int buf, int t) {
    char* bbf = lds + buf * PER_BUF + 32768 + w * (BCH * 1024);
    const char* bs = Bsrc + (size_t)t * 128;
#pragma unroll
    for (int k = 0; k < BCH; ++k) gload16(bs + (size_t)k * 16384, bbf + k * 1024);
  };

// load A-frag pair (hi,lo) for mi = BASE..BASE+3 into ah[], al[]
#define LOADA(BASE)                                                              \
  {                                                                              \
    _Pragma("unroll") for (int u = 0; u < 4; ++u) {                              \
      const int mi = (BASE) + u;                                                 \
      if constexpr (AMODE == 0) {                                                \
        ah[u] = *(const short8*)(bp + afr + mi * 2048 + hi16);                   \
        al[u] = *(const short8*)(bp + afr + mi * 2048 + (hi16 ^ 16));            \
      } else {                                                                   \
        float4 f0 = *(const float4*)(bp + afr + mi * 2048 + hi16);               \
        float4 f1 = *(const float4*)(bp + afr + mi * 2048 + (hi16 ^ 16));        \
        const float fv[8] = {f0.x, f0.y, f0.z, f0.w, f1.x, f1.y, f1.z, f1.w};    \
        _Pragma("unroll") for (int e = 0; e < 8; ++e) {                          \
          uint16_t hb, lb;                                                       \
          split2(fv[e], hb, lb);                                                 \
          ah[u][e] = (short)hb;                                                  \
          al[u][e] = (short)lb;                                                  \
        }                                                                        \
      }                                                                          \
    }                                                                            \
  }

// 48 MFMAs (BN=256) for mi = BASE..BASE+3, pass-major; per-acc order hh->hl->lh
#define MFMA48(BASE)                                                             \
  {                                                                              \
    __builtin_amdgcn_s_setprio(1);                                               \
    _Pragma("unroll") for (int u = 0; u < 4; ++u)                                \
      _Pragma("unroll") for (int ni = 0; ni < NFR; ++ni)                         \
        acc[(BASE) + u][ni] = __builtin_amdgcn_mfma_f32_16x16x32_bf16(           \
            ah[u], bh[ni], acc[(BASE) + u][ni], 0, 0, 0);                        \
    _Pragma("unroll") for (int u = 0; u < 4; ++u)                                \
      _Pragma("unroll") for (int ni = 0; ni < NFR; ++ni)                         \
        acc[(BASE) + u][ni] = __builtin_amdgcn_mfma_f32_16x16x32_bf16(           \
            ah[u], bl[ni], acc[(BASE) + u][ni], 0, 0, 0);                        \
    _Pragma("unroll") for (int u = 0; u < 4; ++u)                                \
      _Pragma("unroll") for (int ni = 0; ni < NFR; ++ni)                         \
        acc[(BASE) + u][ni] = __builtin_amdgcn_mfma_f32_16x16x32_bf16(           \
            al[u], bh[ni], acc[(BASE) + u][ni], 0, 0, 0);                        \
    __builtin_amdgcn_s_setprio(0);                                               \
  }

  stage_a(0, 0);
  stage_b(0, 0);
  int cur = 0;
#pragma unroll 2
  for (int t = 0; t < 16; ++t) {
    // tile-top fence: per-wave drain of tile t's stages, then block-wide sync.
    // (only tile t's loads are outstanding here -> no prefetch is drained.)
    asm volatile("s_waitcnt vmcnt(0)" ::: "memory");
    __builtin_amdgcn_s_barrier();
    asm volatile("" ::: "memory");

    const char* bp = lds + cur * PER_BUF;
    if (t < 15) stage_a(cur ^ 1, t + 1);  // safe: all waves past barrier

    short8 bh[NFR], bl[NFR];
#pragma unroll
    for (int ni = 0; ni < NFR; ++ni) {
      bh[ni] = *(const short8*)(bp + bfr + ni * 2048 + hi16);
      bl[ni] = *(const short8*)(bp + bfr + ni * 2048 + (hi16 ^ 16));
    }
    short8 ah[4], al[4];
    LOADA(0)
    MFMA48(0)
    if (t < 15) stage_b(cur ^ 1, t + 1);
    LOADA(4)
    MFMA48(4)
    cur ^= 1;
  }
#undef LOADA
#undef MFMA48

#pragma unroll
  for (int mi = 0; mi < 8; ++mi) {
    const int row = bm + wr * 128 + mi * 16 + lk * 4;
#pragma unroll
    for (int ni = 0; ni < NFR; ++ni) {
      const int col = bn + wc * (BN / 4) + ni * 16 + lrow;
      const float bc = bias[col];
#pragma unroll
      for (int j = 0; j < 4; ++j) {
        const float vv = acc[mi][ni][j] + bc;
        if constexpr (EPI == 0) {
          outf[(size_t)(row + j) * N + col] = vv;
        } else if constexpr (EPI == 1) {
          uint16_t hb, lb;
          split2(vv, hb, lb);
          char* p = outb + (size_t)(row + j) * 2048 + (col >> 3) * 32 + (col & 7) * 2;
          *(uint16_t*)p = hb;
          *(uint16_t*)(p + 16) = lb;
        } else {
          ((bf16*)outb)[(size_t)(row + j) * 512 + col] = __float2bfloat16(vv);
        }
      }
    }
  }
}

// ---------------- final plain GEMM: out[M,256] = h_hi @ Wb.T + bb ----------------
__global__ __launch_bounds__(256) void gemm_final(const char* __restrict__ Aio,
                                                  const bf16* __restrict__ Wb,
                                                  const float* __restrict__ bias,
                                                  float* __restrict__ out) {
  __shared__ __align__(16) char lds[32768];  // 2 bufs x (A 8KB | B 8KB)
  const int tid = threadIdx.x, w = tid >> 6, l = tid & 63;
  const int bn = blockIdx.x * 128, bm = blockIdx.y * 128;

  const int srow = l >> 2;
  const int ss = (l & 3) ^ (srow & 3);
  const char* Asrc = Aio + (size_t)(bm + srow) * 2048 + ss * 32;  // hi chunks @32B stride
  const char* Bsrc = (const char*)Wb + (size_t)(bn + srow) * 1024 + ss * 16;

  const int lrow = l & 15, lk = l >> 4;
  const int wr = w >> 1, wc = w & 1;
  const int abase = (wr * 64 + lrow) * 64;
  const int bbase = 8192 + (wc * 64 + lrow) * 64;
  const int sf = (lk ^ (lrow & 3)) * 16;

  f32x4 acc[4][4] = {};
  auto stage = [&](int buf, int t) {
#pragma unroll
    for (int c = 0; c < 2; ++c) {
      const int i = w * 2 + c;
      gload16(Asrc + (size_t)i * 16 * 2048 + (size_t)t * 128, lds + buf * 16384 + i * 1024);
      gload16(Bsrc + (size_t)i * 16 * 1024 + (size_t)t * 64, lds + buf * 16384 + 8192 + i * 1024);
    }
  };
  stage(0, 0);
  __syncthreads();
  int cur = 0;
  for (int t = 0; t < 16; ++t) {
    if (t < 15) stage(cur ^ 1, t + 1);
    const char* bp = lds + cur * 16384;
    short8 af[4], bf_[4];
#pragma unroll
    for (int i = 0; i < 4; ++i) {
      af[i] = *(const short8*)(bp + abase + i * 1024 + sf);
      bf_[i] = *(const short8*)(bp + bbase + i * 1024 + sf);
    }
#pragma unroll
    for (int mi = 0; mi < 4; ++mi)
#pragma unroll
      for (int ni = 0; ni < 4; ++ni)
        acc[mi][ni] = __builtin_amdgcn_mfma_f32_16x16x32_bf16(af[mi], bf_[ni], acc[mi][ni], 0, 0, 0);
    __syncthreads();
    cur ^= 1;
  }
#pragma unroll
  for (int mi = 0; mi < 4; ++mi) {
    const int row = bm + wr * 64 + mi * 16 + lk * 4;
#pragma unroll
    for (int ni = 0; ni < 4; ++ni) {
      const int col = bn + wc * 64 + ni * 16 + lrow;
      const float bc = bias[col];
#pragma unroll
      for (int j = 0; j < 4; ++j)
        out[(size_t)(row + j) * 256 + col] = acc[mi][ni][j] + bc;
    }
  }
}

// ---------------- BN stats on io-format h ----------------
__global__ __launch_bounds__(256) void stats_io(const char* __restrict__ Hio,
                                                float* __restrict__ part) {
  __shared__ float sm[4096];
  const int t = threadIdx.x;
  const int chunk = t & 63, grp = t >> 6;
  const int r0 = blockIdx.x * 448 + grp * 112;
  float s[8] = {}, q[8] = {};
  for (int r = r0; r < r0 + 112; ++r) {
    const char* p = Hio + (size_t)r * 2048 + chunk * 32;
    uint4 hh = *(const uint4*)p, hl = *(const uint4*)(p + 16);
#pragma unroll
    for (int e = 0; e < 8; ++e) {
      float v = h16(hh, e) + h16(hl, e);
      s[e] += v;
      q[e] += v * v;
    }
  }
#pragma unroll
  for (int e = 0; e < 8; ++e) {
    sm[grp * 512 + chunk * 8 + e] = s[e];
    sm[2048 + grp * 512 + chunk * 8 + e] = q[e];
  }
  __syncthreads();
  float* pb = part + (size_t)blockIdx.x * 1024;
#pragma unroll
  for (int cc = 0; cc < 2; ++cc) {
    const int c = t * 2 + cc;
    float ssum = sm[c] + sm[512 + c] + sm[1024 + c] + sm[1536 + c];
    float qsum = sm[2048 + c] + sm[2560 + c] + sm[3072 + c] + sm[3584 + c];
    pb[c] = ssum;
    pb[512 + c] = qsum;
  }
}

__global__ __launch_bounds__(64) void reduce_stats(const float* __restrict__ part,
                                                   const float* __restrict__ g,
                                                   const float* __restrict__ bb,
                                                   float* __restrict__ sv,
                                                   float* __restrict__ tv) {
  const int c = blockIdx.x, k = threadIdx.x;
  float sum = 0.f, sq = 0.f;
#pragma unroll
  for (int j = 0; j < 4; ++j) {
    const float* p = part + (size_t)(k + 64 * j) * 1024;
    sum += p[c];
    sq += p[512 + c];
  }
#pragma unroll
  for (int o = 32; o; o >>= 1) {
    sum += __shfl_xor(sum, o);
    sq += __shfl_xor(sq, o);
  }
  if (k == 0) {
    const float mean = sum * (1.0f / 114688.0f);
    const float var = sq * (1.0f / 114688.0f) - mean * mean;
    const float sc = g[c] * rsqrtf(var + 1e-5f);
    sv[c] = sc;
    tv[c] = bb[c] - mean * sc;
  }
}

// ---------------- fused attention + residual + relu, in place on h ----------------
__global__ __launch_bounds__(256) void attn_relu(const float* __restrict__ qkf,
                                                 const bf16* __restrict__ V,
                                                 char* __restrict__ Hio,
                                                 const float* __restrict__ sv,
                                                 const float* __restrict__ tv) {
  const int w = threadIdx.x >> 6, l = threadIdx.x & 63;
  const int b = blockIdx.x * 4 + w;
  const size_t base = (size_t)b * 7;

  float qv[7], kv[7];
#pragma unroll
  for (int i = 0; i < 7; ++i) {
    qv[i] = qkf[(base + i) * 128 + l];
    kv[i] = qkf[(base + i) * 128 + 64 + l];
  }
  float att[7][7];
#pragma unroll
  for (int i = 0; i < 7; ++i)
#pragma unroll
    for (int j = 0; j < 7; ++j) {
      float p = qv[i] * kv[j];
#pragma unroll
      for (int o = 32; o; o >>= 1) p += __shfl_xor(p, o);
      att[i][j] = p;
    }
#pragma unroll
  for (int i = 0; i < 7; ++i) {
    float m = att[i][0];
#pragma unroll
    for (int j = 1; j < 7; ++j) m = fmaxf(m, att[i][j]);
    float sum = 0.f;
#pragma unroll
    for (int j = 0; j < 7; ++j) {
      att[i][j] = expf(att[i][j] - m);
      sum += att[i][j];
    }
    const float inv = 1.0f / sum;
#pragma unroll
    for (int j = 0; j < 7; ++j) att[i][j] *= inv;
  }

  const float4 s0 = *(const float4*)&sv[l * 8], s1 = *(const float4*)&sv[l * 8 + 4];
  const float4 t0 = *(const float4*)&tv[l * 8], t1 = *(const float4*)&tv[l * 8 + 4];
  const float sarr[8] = {s0.x, s0.y, s0.z, s0.w, s1.x, s1.y, s1.z, s1.w};
  const float tarr[8] = {t0.x, t0.y, t0.z, t0.w, t1.x, t1.y, t1.z, t1.w};

  uint4 vpk[7];
#pragma unroll
  for (int j = 0; j < 7; ++j)
    vpk[j] = *(const uint4*)((const char*)V + (base + j) * 1024 + l * 16);

#pragma unroll
  for (int i = 0; i < 7; ++i) {
    char* hp = Hio + (base + i) * 2048 + l * 32;
    uint4 hh = *(const uint4*)hp;
    uint4 hl = *(const uint4*)(hp + 16);
    float o[8] = {};
#pragma unroll
    for (int j = 0; j < 7; ++j) {
      const float a = att[i][j];
#pragma unroll
      for (int e = 0; e < 8; ++e) o[e] += a * h16(vpk[j], e);
    }
    uint16_t oh[8], ol[8];
#pragma unroll
    for (int e = 0; e < 8; ++e) {
      const float hval = h16(hh, e) + h16(hl, e);
      const float r = fmaxf(o[e] + hval * sarr[e] + tarr[e], 0.f);
      split2(r, oh[e], ol[e]);
    }
    uint4 ph, pl;
#pragma unroll
    for (int k2 = 0; k2 < 4; ++k2) {
      ((uint32_t*)&ph)[k2] = (uint32_t)oh[2 * k2] | ((uint32_t)oh[2 * k2 + 1] << 16);
      ((uint32_t*)&pl)[k2] = (uint32_t)ol[2 * k2] | ((uint32_t)ol[2 * k2 + 1] << 16);
    }
    *(uint4*)hp = ph;
    *(uint4*)(hp + 16) = pl;
  }
}

extern "C" void kernel_launch(void* const* d_in, const int* in_sizes, int n_in,
                              void* d_out, int out_size, void* d_ws, size_t ws_size,
                              hipStream_t stream) {
  const float* x  = (const float*)d_in[0];
  const float* Wt = (const float*)d_in[1];
  const float* bt = (const float*)d_in[2];
  const float *bng[3], *bnb[3], *Wq[3], *bq[3], *Wk[3], *bk[3], *Wv[3], *bv[3], *gam[3];
  for (int i = 0; i < 3; ++i) {
    int o = 3 + 9 * i;
    bng[i] = (const float*)d_in[o + 0];
    bnb[i] = (const float*)d_in[o + 1];
    Wq[i]  = (const float*)d_in[o + 2];
    bq[i]  = (const float*)d_in[o + 3];
    Wk[i]  = (const float*)d_in[o + 4];
    bk[i]  = (const float*)d_in[o + 5];
    Wv[i]  = (const float*)d_in[o + 6];
    bv[i]  = (const float*)d_in[o + 7];
    gam[i] = (const float*)d_in[o + 8];
  }
  const float* Wb = (const float*)d_in[30];
  const float* bb = (const float*)d_in[31];

  char* ws = (char*)d_ws;
  char*  Hio   = ws;                               // 235,929,600 (114688 x 2048B)
  char*  V     = ws + 235929600;                   // 117,440,512 (plain bf16)
  float* part  = (float*)(ws + 353370112);         // 1,048,576
  float* sv    = (float*)(ws + 354418688);         // 2,048
  float* tv    = (float*)(ws + 354420736);         // 2,048
  char*  WqkIo = ws + 354422784;                   // 262,144 (128 rows io)
  float* bqkf  = (float*)(ws + 354684928);         // 2,048
  char*  WvIo  = ws + 354686976;                   // 1,048,576 (512 rows io)
  float* bvf   = (float*)(ws + 355735552);         // 2,048
  char*  WtIo  = ws + 355737600;                   // 1,048,576
  float* btf   = (float*)(ws + 356786176);         // 2,048
  bf16*  Wbbf  = (bf16*)(ws + 356788224);          // 262,144
  float* qkf   = (float*)d_out;                    // 58,720,256 <= out bytes (117MB)

  // weight prep
  cvt4<<<128, 256, 0, stream>>>(Wb, Wbbf, 32768);
  fold_w_io<<<512, 512, 0, stream>>>(Wt, bt, nullptr, nullptr, nullptr, WtIo, btf);

  // h0 = x @ Wt.T + bt   (A = f32 x, split in-register; io out)
  sgemm256<1, 1, 256><<<dim3(2, 448), 512, 0, stream>>>((const char*)x, WtIo, btf,
                                                        nullptr, Hio, 512);

  for (int i = 0; i < 3; ++i) {
    stats_io<<<256, 256, 0, stream>>>(Hio, part);
    reduce_stats<<<512, 64, 0, stream>>>(part, bng[i], bnb[i], sv, tv);
    fold_w_io<<<64, 512, 0, stream>>>(Wq[i], bq[i], sv, tv, nullptr, WqkIo, bqkf);
    fold_w_io<<<64, 512, 0, stream>>>(Wk[i], bk[i], sv, tv, nullptr,
                                      WqkIo + (size_t)64 * 2048, bqkf + 64);
    fold_w_io<<<512, 512, 0, stream>>>(Wv[i], bv[i], sv, tv, gam[i], WvIo, bvf);
    // q|k = h @ Wqk'.T + b'  (f32 out on d_out)
    sgemm256<0, 0, 128><<<dim3(1, 448), 512, 0, stream>>>(Hio, WqkIo, bqkf, qkf, nullptr, 128);
    // v' = h @ (gam*Wv*s)'.T + b''  (plain bf16 out)
    sgemm256<0, 2, 256><<<dim3(2, 448), 512, 0, stream>>>(Hio, WvIo, bvf, nullptr, V, 512);
    // h = relu(att@v' + h*s + t)  in place
    attn_relu<<<4096, 256, 0, stream>>>(qkf, (const bf16*)V, Hio, sv, tv);
  }

  // out = h3_hi @ Wb.T + bb
  gemm_final<<<dim3(2, 896), 256, 0, stream>>>(Hio, Wbbf, bb, (float*)d_out);
}

// Round 8
// 1477.374 us; speedup vs baseline: 1.1823x; 1.1192x over previous
//
#include <hip/hip_runtime.h>
#include <hip/hip_bf16.h>
#include <stdint.h>

// LevelReasoning on MI355X — round 8: r7 structure with V reverted to 3-pass.
// * BM=224 tiles: even CU rounds (1024/512 blocks), whole attn groups per block
// * BN stats fused into gemm1 + attn epilogues (stats_io passes deleted)
// * ALL split GEMMs 3-pass (1-pass V failed: logit amplification ~10x, r7 post-mortem)
// Same single-barrier K-tile pipeline as round 6.

using bf16 = __hip_bfloat16;
typedef __attribute__((ext_vector_type(8))) short short8;
typedef __attribute__((ext_vector_type(4))) float f32x4;

__device__ inline uint16_t f2b_bits(float f) {
  bf16 h = __float2bfloat16(f);
  return __builtin_bit_cast(uint16_t, h);
}
__device__ inline float b2f_bits(uint16_t u) { return __uint_as_float(((uint32_t)u) << 16); }
__device__ inline float bflo(uint32_t u) { return __uint_as_float((u & 0xffffu) << 16); }
__device__ inline float bfhi(uint32_t u) { return __uint_as_float(u & 0xffff0000u); }
__device__ inline void split2(float v, uint16_t& hi, uint16_t& lo) {
  hi = f2b_bits(v);
  lo = f2b_bits(v - b2f_bits(hi));
}
__device__ inline float h16(const uint4& u, int e) {
  uint32_t wrd = ((const uint32_t*)&u)[e >> 1];
  return (e & 1) ? bfhi(wrd) : bflo(wrd);
}

typedef const __attribute__((address_space(1))) void* gas_ptr;
typedef __attribute__((address_space(3))) void* las_ptr;
__device__ inline void gload16(const void* g, void* l) {
  __builtin_amdgcn_global_load_lds((gas_ptr)g, (las_ptr)l, 16, 0, 0);
}

// ---------------- f32 -> bf16 (plain, for Wb) ----------------
__global__ __launch_bounds__(256) void cvt4(const float* __restrict__ in,
                                            bf16* __restrict__ out, int n4) {
  int i = blockIdx.x * 256 + threadIdx.x;
  const int stride = gridDim.x * 256;
  for (; i < n4; i += stride) {
    float4 v = ((const float4*)in)[i];
    uint32_t lo = (uint32_t)f2b_bits(v.x) | ((uint32_t)f2b_bits(v.y) << 16);
    uint32_t hi = (uint32_t)f2b_bits(v.z) | ((uint32_t)f2b_bits(v.w) << 16);
    ((uint2*)out)[i] = make_uint2(lo, hi);
  }
}

// ---------------- fold weight to io-format: W' = g*W*diag(s), b' = g*(b + t@W.T) ----------------
__global__ __launch_bounds__(512) void fold_w_io(const float* __restrict__ Wsrc,
                                                 const float* __restrict__ bsrc,
                                                 const float* __restrict__ sv,
                                                 const float* __restrict__ tv,
                                                 const float* __restrict__ gamp,
                                                 char* __restrict__ Wio,
                                                 float* __restrict__ bout) {
  const int row = blockIdx.x, c = threadIdx.x;
  __shared__ float red[512];
  const float wv = Wsrc[(size_t)row * 512 + c];
  const float g = gamp ? gamp[0] : 1.0f;
  const float s = sv ? sv[c] : 1.0f;
  uint16_t hb, lb;
  split2(g * wv * s, hb, lb);
  char* p = Wio + (size_t)row * 2048 + (c >> 3) * 32 + (c & 7) * 2;
  *(uint16_t*)p = hb;
  *(uint16_t*)(p + 16) = lb;
  red[c] = tv ? wv * tv[c] : 0.0f;
  __syncthreads();
#pragma unroll
  for (int off = 256; off > 0; off >>= 1) {
    if (c < off) red[c] += red[c + off];
    __syncthreads();
  }
  if (c == 0) bout[row] = g * (bsrc[row] + red[0]);
}

// ---------------- 224-row-tile split GEMM, 8 waves, single barrier per K-tile ---------------
// AMODE 0: A io-format split bf16 (2KB rows). AMODE 1: A f32 (2KB rows), split in-reg.
// EPI 0: outf[row*N+col]=acc+bias. EPI 1: io-format out + per-channel stats partials.
// EPI 2: plain bf16 out, pitch 512.  NPASS: 3 = split (hh+hl+lh), 1 = hi*hi only.
template <int AMODE, int EPI, int BN, int NPASS>
__global__ __launch_bounds__(512, 1) void sgemm(const char* __restrict__ A,
                                                const char* __restrict__ Wio,
                                                const float* __restrict__ bias,
                                                float* __restrict__ outf,
                                                char* __restrict__ outb,
                                                float* __restrict__ part, int N) {
  constexpr int NFR = BN / 64;              // B frags per wave (n dir)
  constexpr int A_BYTES = 224 * 128;        // 28672
  constexpr int PER_BUF = A_BYTES + BN * 128;
  constexpr int NB_K = BN / 64;             // B stage instrs per wave
  __shared__ __align__(16) char lds[2 * PER_BUF];
  __shared__ float sred[2][2][256];         // [s|q][wr][col_local] (EPI==1)
  const int tid = threadIdx.x, w = tid >> 6, l = tid & 63;

  // XCD-chunked bijective block swizzle (nwg % 8 == 0 for all our grids)
  const int nwgx = gridDim.x;
  const int raw = blockIdx.y * nwgx + blockIdx.x;
  const int cpx = (nwgx * gridDim.y) >> 3;
  const int work = (raw & 7) * cpx + (raw >> 3);
  const int bmidx = work / nwgx;
  const int bm = bmidx * 224;
  const int bn = (work % nwgx) * BN;

  // staging lane geometry: lane l covers row (i*8 + (l>>3)), swizzled 32B pair + 16B piece
  const int ssl = ((((l >> 1) & 3) ^ ((l >> 3) & 3)) << 5) | (((l & 1) ^ ((l >> 5) & 1)) << 4);
  const char* Asrc = A + (size_t)(bm + (l >> 3)) * 2048 + ssl;
  const char* Bsrc = Wio + (size_t)(bn + (l >> 3)) * 2048 + ssl;

  // fragment-read geometry
  const int lrow = l & 15, lk = l >> 4;
  const int wr = w >> 2, wc = w & 3;        // 2x4 wave grid; wave tile 112 x (BN/4)
  const int sw32 = (lk ^ (lrow & 3)) * 32;
  const int hi16 = ((lrow >> 2) & 1) * 16;  // physical slot of the hi piece
  const int afr = (wr * 112 + lrow) * 128 + sw32;                 // + mi*2048
  const int bfr = A_BYTES + (wc * (BN / 4) + lrow) * 128 + sw32;  // + ni*2048

  f32x4 acc[7][NFR] = {};

  auto stage_a = [&](int buf, int t) {
    char* dst = lds + buf * PER_BUF;
    const char* src = Asrc + (size_t)t * 128;
#pragma unroll
    for (int k = 0; k < 4; ++k) {
      const int i = w + k * 8;              // 28 instrs total, 8 rows each
      if (k < 3 || w < 4) gload16(src + (size_t)i * 16384, dst + i * 1024);
    }
  };
  auto stage_b = [&](int buf, int t) {
    char* dst = lds + buf * PER_BUF + A_BYTES;
    const char* src = Bsrc + (size_t)t * 128;
#pragma unroll
    for (int k = 0; k < NB_K; ++k) {
      const int i = w + k * 8;
      gload16(src + (size_t)i * 16384, dst + i * 1024);
    }
  };

#define LOADA(BASE, CNT)                                                         \
  {                                                                              \
    _Pragma("unroll") for (int u = 0; u < (CNT); ++u) {                          \
      const int mi = (BASE) + u;                                                 \
      if constexpr (AMODE == 0) {                                                \
        ah[u] = *(const short8*)(bp + afr + mi * 2048 + hi16);                   \
        if constexpr (NPASS == 3)                                                \
          al[u] = *(const short8*)(bp + afr + mi * 2048 + (hi16 ^ 16));          \
      } else {                                                                   \
        float4 f0 = *(const float4*)(bp + afr + mi * 2048 + hi16);               \
        float4 f1 = *(const float4*)(bp + afr + mi * 2048 + (hi16 ^ 16));        \
        const float fv[8] = {f0.x, f0.y, f0.z, f0.w, f1.x, f1.y, f1.z, f1.w};    \
        _Pragma("unroll") for (int e = 0; e < 8; ++e) {                          \
          uint16_t hb, lb;                                                       \
          split2(fv[e], hb, lb);                                                 \
          ah[u][e] = (short)hb;                                                  \
          al[u][e] = (short)lb;                                                  \
        }                                                                        \
      }                                                                          \
    }                                                                            \
  }

#define MFMAC(BASE, CNT)                                                         \
  {                                                                              \
    __builtin_amdgcn_s_setprio(1);                                               \
    _Pragma("unroll") for (int u = 0; u < (CNT); ++u)                            \
      _Pragma("unroll") for (int ni = 0; ni < NFR; ++ni)                         \
        acc[(BASE) + u][ni] = __builtin_amdgcn_mfma_f32_16x16x32_bf16(           \
            ah[u], bh[ni], acc[(BASE) + u][ni], 0, 0, 0);                        \
    if constexpr (NPASS == 3) {                                                  \
      _Pragma("unroll") for (int u = 0; u < (CNT); ++u)                          \
        _Pragma("unroll") for (int ni = 0; ni < NFR; ++ni)                       \
          acc[(BASE) + u][ni] = __builtin_amdgcn_mfma_f32_16x16x32_bf16(         \
              ah[u], bl[ni], acc[(BASE) + u][ni], 0, 0, 0);                      \
      _Pragma("unroll") for (int u = 0; u < (CNT); ++u)                          \
        _Pragma("unroll") for (int ni = 0; ni < NFR; ++ni)                       \
          acc[(BASE) + u][ni] = __builtin_amdgcn_mfma_f32_16x16x32_bf16(         \
              al[u], bh[ni], acc[(BASE) + u][ni], 0, 0, 0);                      \
    }                                                                            \
    __builtin_amdgcn_s_setprio(0);                                               \
  }

  stage_a(0, 0);
  stage_b(0, 0);
  int cur = 0;
#pragma unroll 2
  for (int t = 0; t < 16; ++t) {
    asm volatile("s_waitcnt vmcnt(0)" ::: "memory");
    __builtin_amdgcn_s_barrier();
    asm volatile("" ::: "memory");

    const char* bp = lds + cur * PER_BUF;
    if (t < 15) stage_a(cur ^ 1, t + 1);

    short8 bh[NFR], bl[NFR];
#pragma unroll
    for (int ni = 0; ni < NFR; ++ni) {
      bh[ni] = *(const short8*)(bp + bfr + ni * 2048 + hi16);
      if constexpr (NPASS == 3)
        bl[ni] = *(const short8*)(bp + bfr + ni * 2048 + (hi16 ^ 16));
    }
    short8 ah[4], al[4];
    LOADA(0, 4)
    MFMAC(0, 4)
    if (t < 15) stage_b(cur ^ 1, t + 1);
    LOADA(4, 3)
    MFMAC(4, 3)
    cur ^= 1;
  }
#undef LOADA
#undef MFMAC

  float sni[NFR] = {}, qni[NFR] = {};
#pragma unroll
  for (int mi = 0; mi < 7; ++mi) {
    const int row = bm + wr * 112 + mi * 16 + lk * 4;
#pragma unroll
    for (int ni = 0; ni < NFR; ++ni) {
      const int col = bn + wc * (BN / 4) + ni * 16 + lrow;
      const float bc = bias[col];
#pragma unroll
      for (int j = 0; j < 4; ++j) {
        const float vv = acc[mi][ni][j] + bc;
        if constexpr (EPI == 0) {
          outf[(size_t)(row + j) * N + col] = vv;
        } else if constexpr (EPI == 1) {
          uint16_t hb, lb;
          split2(vv, hb, lb);
          char* p = outb + (size_t)(row + j) * 2048 + (col >> 3) * 32 + (col & 7) * 2;
          *(uint16_t*)p = hb;
          *(uint16_t*)(p + 16) = lb;
          sni[ni] += vv;
          qni[ni] += vv * vv;
        } else {
          ((bf16*)outb)[(size_t)(row + j) * 512 + col] = __float2bfloat16(vv);
        }
      }
    }
  }

  if constexpr (EPI == 1) {
    // per-channel partials over this block's 224 rows -> part[bmidx]
#pragma unroll
    for (int ni = 0; ni < NFR; ++ni) {
      float s = sni[ni], q = qni[ni];
      s += __shfl_xor(s, 16); q += __shfl_xor(q, 16);
      s += __shfl_xor(s, 32); q += __shfl_xor(q, 32);
      if (lk == 0) {
        sred[0][wr][wc * 64 + ni * 16 + lrow] = s;
        sred[1][wr][wc * 64 + ni * 16 + lrow] = q;
      }
    }
    __syncthreads();
    if (tid < 256) {
      part[(size_t)bmidx * 1024 + bn + tid] = sred[0][0][tid] + sred[0][1][tid];
      part[(size_t)bmidx * 1024 + 512 + bn + tid] = sred[1][0][tid] + sred[1][1][tid];
    }
  }
}

// ---------------- final plain GEMM: out[M,256] = h_hi @ Wb.T + bb ----------------
__global__ __launch_bounds__(256) void gemm_final(const char* __restrict__ Aio,
                                                  const bf16* __restrict__ Wb,
                                                  const float* __restrict__ bias,
                                                  float* __restrict__ out) {
  __shared__ __align__(16) char lds[32768];
  const int tid = threadIdx.x, w = tid >> 6, l = tid & 63;
  const int bn = blockIdx.x * 128, bm = blockIdx.y * 128;

  const int srow = l >> 2;
  const int ss = (l & 3) ^ (srow & 3);
  const char* Asrc = Aio + (size_t)(bm + srow) * 2048 + ss * 32;
  const char* Bsrc = (const char*)Wb + (size_t)(bn + srow) * 1024 + ss * 16;

  const int lrow = l & 15, lk = l >> 4;
  const int wr = w >> 1, wc = w & 1;
  const int abase = (wr * 64 + lrow) * 64;
  const int bbase = 8192 + (wc * 64 + lrow) * 64;
  const int sf = (lk ^ (lrow & 3)) * 16;

  f32x4 acc[4][4] = {};
  auto stage = [&](int buf, int t) {
#pragma unroll
    for (int c = 0; c < 2; ++c) {
      const int i = w * 2 + c;
      gload16(Asrc + (size_t)i * 16 * 2048 + (size_t)t * 128, lds + buf * 16384 + i * 1024);
      gload16(Bsrc + (size_t)i * 16 * 1024 + (size_t)t * 64, lds + buf * 16384 + 8192 + i * 1024);
    }
  };
  stage(0, 0);
  __syncthreads();
  int cur = 0;
  for (int t = 0; t < 16; ++t) {
    if (t < 15) stage(cur ^ 1, t + 1);
    const char* bp = lds + cur * 16384;
    short8 af[4], bf_[4];
#pragma unroll
    for (int i = 0; i < 4; ++i) {
      af[i] = *(const short8*)(bp + abase + i * 1024 + sf);
      bf_[i] = *(const short8*)(bp + bbase + i * 1024 + sf);
    }
#pragma unroll
    for (int mi = 0; mi < 4; ++mi)
#pragma unroll
      for (int ni = 0; ni < 4; ++ni)
        acc[mi][ni] = __builtin_amdgcn_mfma_f32_16x16x32_bf16(af[mi], bf_[ni], acc[mi][ni], 0, 0, 0);
    __syncthreads();
    cur ^= 1;
  }
#pragma unroll
  for (int mi = 0; mi < 4; ++mi) {
    const int row = bm + wr * 64 + mi * 16 + lk * 4;
#pragma unroll
    for (int ni = 0; ni < 4; ++ni) {
      const int col = bn + wc * 64 + ni * 16 + lrow;
      const float bc = bias[col];
#pragma unroll
      for (int j = 0; j < 4; ++j)
        out[(size_t)(row + j) * 256 + col] = acc[mi][ni][j] + bc;
    }
  }
}

// ---------------- stats reduce: part[n][1024] -> sv, tv ----------------
__global__ __launch_bounds__(64) void reduce_stats(const float* __restrict__ part, int n,
                                                   const float* __restrict__ g,
                                                   const float* __restrict__ bb,
                                                   float* __restrict__ sv,
                                                   float* __restrict__ tv) {
  const int c = blockIdx.x, k = threadIdx.x;
  float sum = 0.f, sq = 0.f;
  for (int i = k; i < n; i += 64) {
    const float* p = part + (size_t)i * 1024;
    sum += p[c];
    sq += p[512 + c];
  }
#pragma unroll
  for (int o = 32; o; o >>= 1) {
    sum += __shfl_xor(sum, o);
    sq += __shfl_xor(sq, o);
  }
  if (k == 0) {
    const float mean = sum * (1.0f / 114688.0f);
    const float var = sq * (1.0f / 114688.0f) - mean * mean;
    const float sc = g[c] * rsqrtf(var + 1e-5f);
    sv[c] = sc;
    tv[c] = bb[c] - mean * sc;
  }
}

// ---------------- fused attention + residual + relu (+ stats), in place on h ----------------
template <bool STATS>
__global__ __launch_bounds__(256) void attn_relu(const float* __restrict__ qkf,
                                                 const bf16* __restrict__ V,
                                                 char* __restrict__ Hio,
                                                 const float* __restrict__ sv,
                                                 const float* __restrict__ tv,
                                                 float* __restrict__ part) {
  __shared__ float smS[4][512], smQ[4][512];
  const int w = threadIdx.x >> 6, l = threadIdx.x & 63;
  const int b = blockIdx.x * 4 + w;
  const size_t base = (size_t)b * 7;

  float qv[7], kv[7];
#pragma unroll
  for (int i = 0; i < 7; ++i) {
    qv[i] = qkf[(base + i) * 128 + l];
    kv[i] = qkf[(base + i) * 128 + 64 + l];
  }
  float att[7][7];
#pragma unroll
  for (int i = 0; i < 7; ++i)
#pragma unroll
    for (int j = 0; j < 7; ++j) {
      float p = qv[i] * kv[j];
#pragma unroll
      for (int o = 32; o; o >>= 1) p += __shfl_xor(p, o);
      att[i][j] = p;
    }
#pragma unroll
  for (int i = 0; i < 7; ++i) {
    float m = att[i][0];
#pragma unroll
    for (int j = 1; j < 7; ++j) m = fmaxf(m, att[i][j]);
    float sum = 0.f;
#pragma unroll
    for (int j = 0; j < 7; ++j) {
      att[i][j] = expf(att[i][j] - m);
      sum += att[i][j];
    }
    const float inv = 1.0f / sum;
#pragma unroll
    for (int j = 0; j < 7; ++j) att[i][j] *= inv;
  }

  const float4 s0 = *(const float4*)&sv[l * 8], s1 = *(const float4*)&sv[l * 8 + 4];
  const float4 t0 = *(const float4*)&tv[l * 8], t1 = *(const float4*)&tv[l * 8 + 4];
  const float sarr[8] = {s0.x, s0.y, s0.z, s0.w, s1.x, s1.y, s1.z, s1.w};
  const float tarr[8] = {t0.x, t0.y, t0.z, t0.w, t1.x, t1.y, t1.z, t1.w};

  uint4 vpk[7];
#pragma unroll
  for (int j = 0; j < 7; ++j)
    vpk[j] = *(const uint4*)((const char*)V + (base + j) * 1024 + l * 16);

  float s8[8] = {}, q8[8] = {};
#pragma unroll
  for (int i = 0; i < 7; ++i) {
    char* hp = Hio + (base + i) * 2048 + l * 32;
    uint4 hh = *(const uint4*)hp;
    uint4 hl = *(const uint4*)(hp + 16);
    float o[8] = {};
#pragma unroll
    for (int j = 0; j < 7; ++j) {
      const float a = att[i][j];
#pragma unroll
      for (int e = 0; e < 8; ++e) o[e] += a * h16(vpk[j], e);
    }
    uint16_t oh[8], ol[8];
#pragma unroll
    for (int e = 0; e < 8; ++e) {
      const float hval = h16(hh, e) + h16(hl, e);
      const float r = fmaxf(o[e] + hval * sarr[e] + tarr[e], 0.f);
      if constexpr (STATS) { s8[e] += r; q8[e] += r * r; }
      split2(r, oh[e], ol[e]);
    }
    uint4 ph, pl;
#pragma unroll
    for (int k2 = 0; k2 < 4; ++k2) {
      ((uint32_t*)&ph)[k2] = (uint32_t)oh[2 * k2] | ((uint32_t)oh[2 * k2 + 1] << 16);
      ((uint32_t*)&pl)[k2] = (uint32_t)ol[2 * k2] | ((uint32_t)ol[2 * k2 + 1] << 16);
    }
    *(uint4*)hp = ph;
    *(uint4*)(hp + 16) = pl;
  }

  if constexpr (STATS) {
#pragma unroll
    for (int e = 0; e < 8; ++e) {
      smS[w][l * 8 + e] = s8[e];
      smQ[w][l * 8 + e] = q8[e];
    }
    __syncthreads();
    const int c = threadIdx.x * 2;
#pragma unroll
    for (int cc = 0; cc < 2; ++cc) {
      const int c2 = c + cc;
      part[(size_t)blockIdx.x * 1024 + c2] =
          smS[0][c2] + smS[1][c2] + smS[2][c2] + smS[3][c2];
      part[(size_t)blockIdx.x * 1024 + 512 + c2] =
          smQ[0][c2] + smQ[1][c2] + smQ[2][c2] + smQ[3][c2];
    }
  }
}

extern "C" void kernel_launch(void* const* d_in, const int* in_sizes, int n_in,
                              void* d_out, int out_size, void* d_ws, size_t ws_size,
                              hipStream_t stream) {
  const float* x  = (const float*)d_in[0];
  const float* Wt = (const float*)d_in[1];
  const float* bt = (const float*)d_in[2];
  const float *bng[3], *bnb[3], *Wq[3], *bq[3], *Wk[3], *bk[3], *Wv[3], *bv[3], *gam[3];
  for (int i = 0; i < 3; ++i) {
    int o = 3 + 9 * i;
    bng[i] = (const float*)d_in[o + 0];
    bnb[i] = (const float*)d_in[o + 1];
    Wq[i]  = (const float*)d_in[o + 2];
    bq[i]  = (const float*)d_in[o + 3];
    Wk[i]  = (const float*)d_in[o + 4];
    bk[i]  = (const float*)d_in[o + 5];
    Wv[i]  = (const float*)d_in[o + 6];
    bv[i]  = (const float*)d_in[o + 7];
    gam[i] = (const float*)d_in[o + 8];
  }
  const float* Wb = (const float*)d_in[30];
  const float* bb = (const float*)d_in[31];

  char* ws = (char*)d_ws;
  char*  Hio   = ws;                               // 235,929,600 (114688 x 2048B)
  char*  V     = ws + 235929600;                   // 117,440,512 (plain bf16)
  float* part  = (float*)(ws + 353370112);         // 16,777,216 (4096 x 1024 f32)
  float* sv    = (float*)(ws + 370147328);         // 2,048
  float* tv    = (float*)(ws + 370149376);         // 2,048
  char*  WqkIo = ws + 370151424;                   // 262,144
  float* bqkf  = (float*)(ws + 370413568);         // 2,048
  char*  WvIo  = ws + 370415616;                   // 1,048,576
  float* bvf   = (float*)(ws + 371464192);         // 2,048
  char*  WtIo  = ws + 371466240;                   // 1,048,576
  float* btf   = (float*)(ws + 372514816);         // 2,048
  bf16*  Wbbf  = (bf16*)(ws + 372516864);          // 262,144
  float* qkf   = (float*)d_out;                    // 58.7 MB <= out bytes (117MB)

  // weight prep
  cvt4<<<128, 256, 0, stream>>>(Wb, Wbbf, 32768);
  fold_w_io<<<512, 512, 0, stream>>>(Wt, bt, nullptr, nullptr, nullptr, WtIo, btf);

  // h0 = x @ Wt.T + bt  (split 3-pass; io out + stats partials)
  sgemm<1, 1, 256, 3><<<dim3(2, 512), 512, 0, stream>>>((const char*)x, WtIo, btf,
                                                        nullptr, Hio, part, 512);

  for (int i = 0; i < 3; ++i) {
    reduce_stats<<<512, 64, 0, stream>>>(part, i == 0 ? 512 : 4096,
                                         bng[i], bnb[i], sv, tv);
    fold_w_io<<<64, 512, 0, stream>>>(Wq[i], bq[i], sv, tv, nullptr, WqkIo, bqkf);
    fold_w_io<<<64, 512, 0, stream>>>(Wk[i], bk[i], sv, tv, nullptr,
                                      WqkIo + (size_t)64 * 2048, bqkf + 64);
    fold_w_io<<<512, 512, 0, stream>>>(Wv[i], bv[i], sv, tv, gam[i], WvIo, bvf);
    // q|k = h @ Wqk'.T + b'  (split 3-pass; f32 out on d_out)
    sgemm<0, 0, 128, 3><<<dim3(1, 512), 512, 0, stream>>>(Hio, WqkIo, bqkf, qkf,
                                                          nullptr, nullptr, 128);
    // v' = h @ (gam*Wv*s)'.T + b''  (split 3-pass; plain bf16 out)
    sgemm<0, 2, 256, 3><<<dim3(2, 512), 512, 0, stream>>>(Hio, WvIo, bvf, nullptr,
                                                          V, nullptr, 512);
    // h = relu(att@v' + h*s + t) in place (+ stats partials for next layer)
    if (i < 2)
      attn_relu<true><<<4096, 256, 0, stream>>>(qkf, (const bf16*)V, Hio, sv, tv, part);
    else
      attn_relu<false><<<4096, 256, 0, stream>>>(qkf, (const bf16*)V, Hio, sv, tv, nullptr);
  }

  // out = h3_hi @ Wb.T + bb
  gemm_final<<<dim3(2, 896), 256, 0, stream>>>(Hio, Wbbf, bb, (float*)d_out);
}